// Round 4
// baseline (209.341 us; speedup 1.0000x reference)
//
#include <hip/hip_runtime.h>
#include <cstdint>
#include <cmath>

#define NROWS 8192
#define KDIM  512            // elements; also bytes/row in fp8
#define NBLK  2048           // gemm grid size (64 x 32)

typedef int    i32x4  __attribute__((ext_vector_type(4)));
typedef int    i32x8  __attribute__((ext_vector_type(8)));
typedef float  f32x16 __attribute__((ext_vector_type(16)));
typedef unsigned char u8;

#define AS1(p) ((const __attribute__((address_space(1))) void*)(p))
#define AS3(p) ((__attribute__((address_space(3))) void*)(p))

// --- Kernel 1: row L2-normalize fp32 -> fp8 e4m3 (OCP, HW cvt), one wave/row.
// zi rows [0,8192), zj rows [8192,16384). Also zeroes accumulators + ticket.
__global__ __launch_bounds__(256) void nrm_kernel(const float* __restrict__ zi,
                                                  const float* __restrict__ zj,
                                                  u8* __restrict__ out,
                                                  double* __restrict__ acc,
                                                  unsigned* __restrict__ cnt) {
    if (blockIdx.x == 0 && threadIdx.x == 0) { acc[0] = 0.0; acc[1] = 0.0; cnt[0] = 0u; }
    const int wave = threadIdx.x >> 6;
    const int lane = threadIdx.x & 63;
    const int row  = blockIdx.x * 4 + wave;            // 0..16383
    const float* src = (row < NROWS) ? zi + (size_t)row * KDIM
                                     : zj + (size_t)(row - NROWS) * KDIM;
    float4 a = ((const float4*)src)[lane];
    float4 b = ((const float4*)src)[lane + 64];
    float ss = a.x*a.x + a.y*a.y + a.z*a.z + a.w*a.w
             + b.x*b.x + b.y*b.y + b.z*b.z + b.w*b.w;
    #pragma unroll
    for (int off = 32; off >= 1; off >>= 1) ss += __shfl_xor(ss, off, 64);
    const float inv = 1.0f / fmaxf(sqrtf(ss), 1e-12f);
    int p0 = 0, p1 = 0;
    p0 = __builtin_amdgcn_cvt_pk_fp8_f32(a.x * inv, a.y * inv, p0, false);
    p0 = __builtin_amdgcn_cvt_pk_fp8_f32(a.z * inv, a.w * inv, p0, true);
    p1 = __builtin_amdgcn_cvt_pk_fp8_f32(b.x * inv, b.y * inv, p1, false);
    p1 = __builtin_amdgcn_cvt_pk_fp8_f32(b.z * inv, b.w * inv, p1, true);
    int* dst = (int*)(out + (size_t)row * KDIM);
    dst[lane]      = p0;
    dst[lane + 64] = p1;
}

// --- Kernel 2: fused MX-fp8 A*B^T -> exp(10*dot) -> global sum -> (last block) loss.
// Block = 256x256 tile, 4 waves in 2x2, each wave 128x128 via 4x4 of 32x32x64 frags.
// Wave tile 128x128 => 1 ds_read_b128 per MFMA (LDS pipe 16 cyc/MFMA < 17.2 capacity,
// vs 32 at 64x64 tiles — R2's measured LDS-pipe oversubscription).
// Single-barrier double-buffered K-loop: stage k+1 issued under iter-k's 16 MFMAs
// (~1100 cyc) so the compiler's vmcnt(0)-before-s_barrier drain is already covered.
// LDS is XOR-swizzled at 16B granularity (verified R2): region = 32 rows x 64 B;
// chunk (r,b) at p = r*4 + (b ^ ((r>>1)&3)); staging inverse b = (lane&3)^((lane>>3)&3).
// Pos-region diagonal skipped, added exactly at finalize. VGPR ~360 -> 1 wave/SIMD.
__global__ __launch_bounds__(256, 1) void gemm_exp_reduce(const u8* __restrict__ A,
                                                          const u8* __restrict__ B,
                                                          double* __restrict__ acc,
                                                          unsigned* __restrict__ cnt,
                                                          float* __restrict__ out) {
    __shared__ u8 lA[2][256 * 64];   // 2 x 16 KB
    __shared__ u8 lB[2][256 * 64];   // 2 x 16 KB
    __shared__ float red[4];

    const int tid  = threadIdx.x;
    const int lane = tid & 63;
    const int wave = tid >> 6;
    const int m0   = blockIdx.y * 256;
    const int n0   = blockIdx.x * 256;
    const int wm   = (wave >> 1) * 128;
    const int wn   = (wave & 1) * 128;

    f32x16 accf[4][4];
    #pragma unroll
    for (int i = 0; i < 4; ++i)
        #pragma unroll
        for (int j = 0; j < 4; ++j)
            #pragma unroll
            for (int r = 0; r < 16; ++r)
                accf[i][j][r] = 0.f;

    // staging: wave stages A and B rows [wave*64, wave*64+64), 4 instrs each;
    // instr c: global row = base + c*16 + (lane>>2), chunk bsw; LDS = wave*4096+c*1024+lane*16
    const int bsw = (lane & 3) ^ ((lane >> 3) & 3);
    const u8* gA0 = A + (size_t)(m0 + wave * 64 + (lane >> 2)) * KDIM + bsw * 16;
    const u8* gB0 = B + (size_t)(n0 + wave * 64 + (lane >> 2)) * KDIM + bsw * 16;
    const int ldsOff = wave * 4096 + lane * 16;

    // fragment read: lane holds row r=lane&31, k-half q=lane>>5 (chunks 2q,2q+1)
    const int r_  = lane & 31;
    const int q_  = lane >> 5;
    const int p16 = (r_ * 4 + ((2 * q_) ^ ((r_ >> 1) & 3))) * 16;
    const int aT0 = (wave >> 1) * 4;   // A regions aT0..aT0+3 (128 rows)
    const int bT0 = (wave & 1) * 4;

    // prologue: stage k=0 into buffer 0
    #pragma unroll
    for (int c = 0; c < 4; ++c) {
        __builtin_amdgcn_global_load_lds(AS1(gA0 + (size_t)c * 16 * KDIM),
                                         AS3(&lA[0][ldsOff + c * 1024]), 16, 0, 0);
        __builtin_amdgcn_global_load_lds(AS1(gB0 + (size_t)c * 16 * KDIM),
                                         AS3(&lB[0][ldsOff + c * 1024]), 16, 0, 0);
    }
    __syncthreads();

    for (int kk = 0; kk < 8; ++kk) {
        const int cur = kk & 1;
        i32x8 af[4], bfr[4];
        #pragma unroll
        for (int mi = 0; mi < 4; ++mi) {
            const int off = (aT0 + mi) * 2048 + p16;
            i32x4 lo = *(const i32x4*)&lA[cur][off];
            i32x4 hi = *(const i32x4*)&lA[cur][off ^ 16];
            af[mi] = (i32x8){lo[0], lo[1], lo[2], lo[3], hi[0], hi[1], hi[2], hi[3]};
        }
        #pragma unroll
        for (int ni = 0; ni < 4; ++ni) {
            const int off = (bT0 + ni) * 2048 + p16;
            i32x4 lo = *(const i32x4*)&lB[cur][off];
            i32x4 hi = *(const i32x4*)&lB[cur][off ^ 16];
            bfr[ni] = (i32x8){lo[0], lo[1], lo[2], lo[3], hi[0], hi[1], hi[2], hi[3]};
        }
        if (kk < 7) {   // issue next tile's staging; drained by this iter's barrier
            const int nxt = cur ^ 1;
            const size_t kb = (size_t)(kk + 1) * 64;
            #pragma unroll
            for (int c = 0; c < 4; ++c) {
                __builtin_amdgcn_global_load_lds(AS1(gA0 + kb + (size_t)c * 16 * KDIM),
                                                 AS3(&lA[nxt][ldsOff + c * 1024]), 16, 0, 0);
                __builtin_amdgcn_global_load_lds(AS1(gB0 + kb + (size_t)c * 16 * KDIM),
                                                 AS3(&lB[nxt][ldsOff + c * 1024]), 16, 0, 0);
            }
        }
        #pragma unroll
        for (int mi = 0; mi < 4; ++mi)
            #pragma unroll
            for (int ni = 0; ni < 4; ++ni)
                accf[mi][ni] = __builtin_amdgcn_mfma_scale_f32_32x32x64_f8f6f4(
                    af[mi], bfr[ni], accf[mi][ni],
                    0, 0,                 // cbsz=fp8(e4m3), blgp=fp8(e4m3)
                    0, 0x7f7f7f7f,        // scale_a: every byte = 2^0
                    0, 0x7f7f7f7f);       // scale_b
        __syncthreads();   // frag reads of buf[cur] done + buf[nxt] staging drained
    }

    // epilogue: exp(10*d) = exp2(d * 10/ln2); skip pos diagonal (bx==by tiles only)
    const float LOG2E10 = 14.4269504088896341f;
    float part = 0.f;
    const bool diagblk = (blockIdx.x == (unsigned)blockIdx.y);   // bx<32 => pos region
    if (diagblk) {
        #pragma unroll
        for (int mi = 0; mi < 4; ++mi)
            #pragma unroll
            for (int ni = 0; ni < 4; ++ni)
                #pragma unroll
                for (int r = 0; r < 16; ++r) {
                    // C/D 32x32: col=lane&31, row=(r&3)+8*(r>>2)+4*(lane>>5)
                    int rr = wm + mi * 32 + ((r & 3) + 8 * (r >> 2) + 4 * (lane >> 5));
                    int cc = wn + ni * 32 + (lane & 31);
                    if (rr != cc) part += exp2f(accf[mi][ni][r] * LOG2E10);
                }
    } else {
        #pragma unroll
        for (int mi = 0; mi < 4; ++mi)
            #pragma unroll
            for (int ni = 0; ni < 4; ++ni)
                #pragma unroll
                for (int r = 0; r < 16; ++r)
                    part += exp2f(accf[mi][ni][r] * LOG2E10);
    }

    #pragma unroll
    for (int off = 32; off >= 1; off >>= 1) part += __shfl_xor(part, off, 64);
    if (lane == 0) red[wave] = part;
    __syncthreads();
    if (tid == 0) {
        double s = (double)red[0] + (double)red[1] + (double)red[2] + (double)red[3];
        atomicAdd(&acc[(blockIdx.x < 32) ? 0 : 1], s);   // n-tile in zi region -> pos
        __threadfence();
        unsigned t = atomicAdd(cnt, 1u);
        if (t == NBLK - 1) {   // last block finalizes: loss = log1p(neg/pos)
            double pos = __hip_atomic_load(&acc[0], __ATOMIC_RELAXED,
                                           __HIP_MEMORY_SCOPE_AGENT) + 8192.0 * exp(10.0);
            double neg = __hip_atomic_load(&acc[1], __ATOMIC_RELAXED,
                                           __HIP_MEMORY_SCOPE_AGENT);
            out[0] = (float)log1p(neg / pos);
        }
    }
}

extern "C" void kernel_launch(void* const* d_in, const int* in_sizes, int n_in,
                              void* d_out, int out_size, void* d_ws, size_t ws_size,
                              hipStream_t stream) {
    const float* zi = (const float*)d_in[0];
    const float* zj = (const float*)d_in[1];
    u8* nrm = (u8*)d_ws;                                      // [16384][512] fp8 = 8 MB
    double* acc = (double*)((char*)d_ws + (size_t)16384 * 512);
    unsigned* cnt = (unsigned*)(acc + 2);

    nrm_kernel<<<4096, 256, 0, stream>>>(zi, zj, nrm, acc, cnt);
    dim3 grid(64, 32);   // x: 16384/256 n-tiles, y: 8192/256 m-tiles
    gemm_exp_reduce<<<grid, 256, 0, stream>>>(nrm, nrm, acc, cnt, (float*)d_out);
}